// Round 8
// baseline (583.767 us; speedup 1.0000x reference)
//
#include <hip/hip_runtime.h>

#define S_ 1024
#define D_ 2048
#define H_ 16
#define HD_ 128
#define E_ 8
#define FI_ 1408
#define FS_ 5632
#define WIN_ 512
#define T_ 1024
#define QKVN 6144

typedef _Float16 f16;
typedef __attribute__((ext_vector_type(8))) _Float16 f16x8;
typedef __attribute__((ext_vector_type(4))) _Float16 f16x4;
typedef __attribute__((ext_vector_type(4))) float f32x4;

#define MFMA16(a, b, c) __builtin_amdgcn_mfma_f32_16x16x32_f16((a), (b), (c), 0, 0, 0)

__device__ __forceinline__ void gload16(const void* g, void* l) {
    __builtin_amdgcn_global_load_lds(
        (const __attribute__((address_space(1))) unsigned*)g,
        (__attribute__((address_space(3))) unsigned*)l, 16, 0, 0);
}

// ---------------- RMSNorm (fp32 in -> f16 out) ----------------
__global__ __launch_bounds__(256) void rmsnorm16_kernel(const float* __restrict__ x,
                                                        const float* __restrict__ w,
                                                        f16* __restrict__ out) {
    int t = blockIdx.x;
    const float* xr = x + (long)t * D_;
    int base = threadIdx.x * 8;
    float4 v0 = *(const float4*)(xr + base);
    float4 v1 = *(const float4*)(xr + base + 4);
    float ss = v0.x*v0.x + v0.y*v0.y + v0.z*v0.z + v0.w*v0.w
             + v1.x*v1.x + v1.y*v1.y + v1.z*v1.z + v1.w*v1.w;
    #pragma unroll
    for (int off = 1; off < 64; off <<= 1) ss += __shfl_xor(ss, off);
    __shared__ float red[4];
    if ((threadIdx.x & 63) == 0) red[threadIdx.x >> 6] = ss;
    __syncthreads();
    float tot = red[0] + red[1] + red[2] + red[3];
    float scale = rsqrtf(tot / (float)D_ + 1e-6f);
    float4 w0 = *(const float4*)(w + base);
    float4 w1 = *(const float4*)(w + base + 4);
    f16x8 o;
    o[0] = (f16)(v0.x*scale*w0.x); o[1] = (f16)(v0.y*scale*w0.y);
    o[2] = (f16)(v0.z*scale*w0.z); o[3] = (f16)(v0.w*scale*w0.w);
    o[4] = (f16)(v1.x*scale*w1.x); o[5] = (f16)(v1.y*scale*w1.y);
    o[6] = (f16)(v1.z*scale*w1.z); o[7] = (f16)(v1.w*scale*w1.w);
    *(f16x8*)(out + (long)t * D_ + base) = o;
}

// ---------------- Transpose+convert: W[K][N] fp32 -> WT f16, vector stores ----------
// mode 0: dst row = n; mode 1 (gate-interleave): row = (n>>4)*32 + (n&15);
// mode 2 (up-interleave): row = (n>>4)*32 + 16 + (n&15)
__device__ __forceinline__ void tconv_body(const float* __restrict__ src,
                                           f16* __restrict__ dst,
                                           int K, int N, int mode) {
    int n0 = blockIdx.x * 64, k0 = blockIdx.y * 64;
    __shared__ f16 tile[64][72];  // [n][k]
    int t = threadIdx.x, r = t >> 2, c4 = (t & 3) * 16;
    const float* sp = src + (long)(k0 + r) * N + n0 + c4;
    #pragma unroll
    for (int i = 0; i < 16; i += 4) {
        float4 v = *(const float4*)(sp + i);
        tile[c4 + i + 0][r] = (f16)v.x;
        tile[c4 + i + 1][r] = (f16)v.y;
        tile[c4 + i + 2][r] = (f16)v.z;
        tile[c4 + i + 3][r] = (f16)v.w;
    }
    __syncthreads();
    #pragma unroll
    for (int h = 0; h < 2; h++) {
        int v = t + h * 256;
        int nl = v >> 3, c8 = (v & 7) * 8;
        f16x8 vec = *(const f16x8*)&tile[nl][c8];
        int nr = n0 + nl;
        long orow = (mode == 0) ? nr
                  : ((long)(nr >> 4) * 32 + (nr & 15) + (mode == 2 ? 16 : 0));
        *(f16x8*)(dst + orow * K + k0 + c8) = vec;
    }
}

__global__ __launch_bounds__(256) void tconv_kernel(const float* __restrict__ src,
                                                    f16* __restrict__ dst,
                                                    int K, int N, long sSrc, long sDst) {
    tconv_body(src + (long)blockIdx.z * sSrc, dst + (long)blockIdx.z * sDst, K, N, 0);
}

// gate+up combined: z < zsplit -> srcA/mode1/e=z ; else srcB/mode2/e=z-zsplit
__global__ __launch_bounds__(256) void tconv_gu_kernel(const float* __restrict__ srcA,
                                                       const float* __restrict__ srcB,
                                                       f16* __restrict__ dst,
                                                       int K, int N, long sSrc, long sDst,
                                                       int zsplit) {
    int z = blockIdx.z;
    int e = (z < zsplit) ? z : z - zsplit;
    const float* src = ((z < zsplit) ? srcA : srcB) + (long)e * sSrc;
    tconv_body(src, dst + (long)e * sDst, K, N, (z < zsplit) ? 1 : 2);
}

// ---------------- GEMM f16: C = A @ BT^T, 2-phase double-buffered LDS ----------------
// EPI: 1 = f16 out + bias_f32[n]; 4 = f32 partial out (plane z);
//      5 = fused silu-pair f16; 6 = f16 out scaled by tw[z*T+m]
// MODE: 0 = normal; 1 = gather A rows via tokidx + early-exit; 2 = early-exit only
template <int EPI, int MODE>
__global__ __launch_bounds__(256) void gemm16_kernel(
    const f16* __restrict__ Ag, const f16* __restrict__ BTg,
    void* Cg, const void* auxg,
    const int* __restrict__ tokidx, const int* __restrict__ cntv,
    const float* __restrict__ tw,
    int M, int N, int K, int lda, int ldb,
    long sA, long sB, long sC) {
    int z = blockIdx.z;
    const f16* A = Ag + (long)z * sA;
    const f16* BT = BTg + (long)z * sB;
    int bm = blockIdx.y * 128, bn = blockIdx.x * 128;
    int cnt = M;
    if (MODE >= 1) {
        cnt = cntv[z];
        if (bm >= cnt) return;
    }
    int tid = threadIdx.x, lane = tid & 63, wave = tid >> 6;
    int wm = (wave >> 1) * 64, wn = (wave & 1) * 64;

    __shared__ f16 As[2][128][64];
    __shared__ f16 Bs[2][128][64];

    f32x4 acc[4][4];
    #pragma unroll
    for (int i = 0; i < 4; i++)
        #pragma unroll
        for (int j = 0; j < 4; j++) acc[i][j] = (f32x4){0.f, 0.f, 0.f, 0.f};

    int srow8 = lane >> 3;
    int scol = ((lane & 7) ^ srow8) * 8;   // pre-swizzled global source
    const f16* Abp[4];
    const f16* Bbp[4];
    #pragma unroll
    for (int i = 0; i < 4; i++) {
        int ra = bm + wave * 32 + i * 8 + srow8;
        long arow;
        if (MODE == 1) {
            int tok = (ra < cnt) ? tokidx[z * T_ + ra] : 0;
            arow = tok;
        } else {
            arow = ra;
        }
        Abp[i] = A + arow * (long)lda + scol;
        Bbp[i] = BT + (long)(bn + wave * 32 + i * 8 + srow8) * ldb + scol;
    }

    auto stage = [&](int b, int k0) {
        #pragma unroll
        for (int i = 0; i < 4; i++) {
            gload16(Abp[i] + k0, &As[b][wave * 32 + i * 8][0]);
            gload16(Bbp[i] + k0, &Bs[b][wave * 32 + i * 8][0]);
        }
    };
    auto compute = [&](int b) {
        #pragma unroll
        for (int kk = 0; kk < 64; kk += 32) {
            f16x8 af[4], bf[4];
            #pragma unroll
            for (int mi = 0; mi < 4; mi++) {
                int r = wm + mi * 16 + (lane & 15);
                int c = ((kk >> 3) + (lane >> 4)) ^ (r & 7);
                af[mi] = *(const f16x8*)((const char*)&As[b][r][0] + (c << 4));
            }
            #pragma unroll
            for (int ni = 0; ni < 4; ni++) {
                int r = wn + ni * 16 + (lane & 15);
                int c = ((kk >> 3) + (lane >> 4)) ^ (r & 7);
                bf[ni] = *(const f16x8*)((const char*)&Bs[b][r][0] + (c << 4));
            }
            #pragma unroll
            for (int mi = 0; mi < 4; mi++)
                #pragma unroll
                for (int ni = 0; ni < 4; ni++)
                    acc[mi][ni] = MFMA16(af[mi], bf[ni], acc[mi][ni]);
        }
    };

    // 2-phase pipeline: stage(next) issued BEFORE compute(cur); one barrier per K-step
    stage(0, 0);
    __syncthreads();
    int cur = 0;
    for (int k0 = 64; k0 < K; k0 += 64) {
        stage(cur ^ 1, k0);
        compute(cur);
        __syncthreads();
        cur ^= 1;
    }
    compute(cur);

    if (EPI == 5) {
        int half = N >> 1;
        #pragma unroll
        for (int mi = 0; mi < 4; mi++) {
            #pragma unroll
            for (int p = 0; p < 2; p++) {
                #pragma unroll
                for (int i = 0; i < 4; i++) {
                    int m = bm + wm + mi * 16 + (lane >> 4) * 4 + i;
                    int j = ((bn + wn) >> 1) + p * 16 + (lane & 15);
                    float g = acc[mi][2 * p][i];
                    float u = acc[mi][2 * p + 1][i];
                    ((f16*)Cg + (long)z * sC)[(long)m * half + j] =
                        (f16)(g / (1.f + __expf(-g)) * u);
                }
            }
        }
        return;
    }
    #pragma unroll
    for (int mi = 0; mi < 4; mi++) {
        #pragma unroll
        for (int ni = 0; ni < 4; ni++) {
            #pragma unroll
            for (int i = 0; i < 4; i++) {
                int m = bm + wm + mi * 16 + (lane >> 4) * 4 + i;
                int n = bn + wn + ni * 16 + (lane & 15);
                long idx = (long)m * N + n;
                float v = acc[mi][ni][i];
                if (EPI == 1) {
                    ((f16*)Cg)[idx] = (f16)(v + ((const float*)auxg)[n]);
                } else if (EPI == 4) {
                    ((float*)Cg + (long)z * sC)[idx] = v;
                } else if (EPI == 6) {
                    float wv = tw[z * T_ + m];
                    ((f16*)Cg + (long)z * sC)[idx] = (f16)(v * wv);
                }
            }
        }
    }
}

// ---------------- RoPE in-place on f16 qkv ----------------
__global__ __launch_bounds__(256) void rope16_kernel(f16* __restrict__ qkv) {
    int s = blockIdx.x;
    float fs = (float)s;
    for (int p = threadIdx.x; p < H_ * 64; p += 256) {
        int h = p >> 6, j = p & 63;
        float inv = __expf(-(float)j * (13.815510557964274f / 64.f));  // 1e6^(-j/64)
        float ang = fs * inv;
        float c = cosf(ang), sn = sinf(ang);
        long base = (long)s * QKVN + h * HD_ + j;
        float q1 = (float)qkv[base], q2 = (float)qkv[base + 64];
        qkv[base] = (f16)(q1 * c - q2 * sn);
        qkv[base + 64] = (f16)(q2 * c + q1 * sn);
        long kb = base + 2048;
        float k1 = (float)qkv[kb], k2 = (float)qkv[kb + 64];
        qkv[kb] = (f16)(k1 * c - k2 * sn);
        qkv[kb + 64] = (f16)(k2 * c + k1 * sn);
    }
}

// ---------------- Sliding-window flash attention (f16) ----------------
__global__ __launch_bounds__(256) void attn16_kernel(const f16* __restrict__ qkv,
                                                     f16* __restrict__ Og) {
    int qt = blockIdx.x * 64;
    int head = blockIdx.y;
    int tid = threadIdx.x, lane = tid & 63, wave = tid >> 6;

    __shared__ f16 Ks[64][128];
    __shared__ f16 Vrow[64][128];
    __shared__ f16 VsT[128][64];
    __shared__ f16 Ps[4][16][64];

    int qr = qt + wave * 16 + (lane & 15);
    const f16* Qp = qkv + (long)qr * QKVN + head * HD_;
    f16x8 qf[4];
    #pragma unroll
    for (int kk = 0; kk < 4; kk++)
        qf[kk] = *(const f16x8*)(Qp + kk * 32 + (lane >> 4) * 8);

    f32x4 oacc[8];
    #pragma unroll
    for (int db = 0; db < 8; db++) oacc[db] = (f32x4){0.f, 0.f, 0.f, 0.f};
    float m_run[4] = {-1e30f, -1e30f, -1e30f, -1e30f};
    float l_run[4] = {0.f, 0.f, 0.f, 0.f};

    int k_lo = qt - (WIN_ - 1);
    if (k_lo < 0) k_lo = 0;
    k_lo &= ~63;

    for (int k0 = k_lo; k0 < qt + 64; k0 += 64) {
        __syncthreads();
        {
            int row = tid >> 2, cq = (tid & 3) * 32;
            const f16* Kp = qkv + (long)(k0 + row) * QKVN + 2048 + head * HD_ + cq;
            const f16* Vp = Kp + 2048;
            #pragma unroll
            for (int u = 0; u < 32; u += 8) {
                f16x8 tk = *(const f16x8*)(Kp + u);
                int co = ((cq + u) * 2) ^ ((row & 7) << 4);
                *(f16x8*)((char*)&Ks[row][0] + co) = tk;
                *(f16x8*)(&Vrow[row][cq + u]) = *(const f16x8*)(Vp + u);
            }
        }
        __syncthreads();
        {
            int d = tid >> 1, ks = (tid & 1) * 32;
            f16 tmp[32];
            #pragma unroll
            for (int j = 0; j < 32; j++) tmp[j] = Vrow[ks + j][d];
            #pragma unroll
            for (int u = 0; u < 32; u += 8) {
                int co = ((ks + u) * 2) ^ ((d & 7) << 4);
                f16x8 tv;
                #pragma unroll
                for (int j = 0; j < 8; j++) tv[j] = tmp[u + j];
                *(f16x8*)((char*)&VsT[d][0] + co) = tv;
            }
        }
        f32x4 sacc[4];
        #pragma unroll
        for (int cb = 0; cb < 4; cb++) sacc[cb] = (f32x4){0.f, 0.f, 0.f, 0.f};
        #pragma unroll
        for (int kk = 0; kk < 4; kk++) {
            #pragma unroll
            for (int cb = 0; cb < 4; cb++) {
                int krow = cb * 16 + (lane & 15);
                int co = ((kk * 32 + (lane >> 4) * 8) * 2) ^ ((krow & 7) << 4);
                f16x8 kf = *(const f16x8*)((const char*)&Ks[krow][0] + co);
                sacc[cb] = MFMA16(qf[kk], kf, sacc[cb]);
            }
        }
        float mtile[4] = {-1e30f, -1e30f, -1e30f, -1e30f};
        #pragma unroll
        for (int cb = 0; cb < 4; cb++) {
            #pragma unroll
            for (int i = 0; i < 4; i++) {
                int qi = qt + wave * 16 + (lane >> 4) * 4 + i;
                int kj = k0 + cb * 16 + (lane & 15);
                float s = sacc[cb][i] * 0.08838834764831845f;
                bool valid = (kj <= qi) && (qi - kj < WIN_);
                s = valid ? s : -1e30f;
                sacc[cb][i] = s;
                mtile[i] = fmaxf(mtile[i], s);
            }
        }
        #pragma unroll
        for (int i = 0; i < 4; i++) {
            float v = mtile[i];
            v = fmaxf(v, __shfl_xor(v, 1));
            v = fmaxf(v, __shfl_xor(v, 2));
            v = fmaxf(v, __shfl_xor(v, 4));
            v = fmaxf(v, __shfl_xor(v, 8));
            mtile[i] = v;
        }
        float pscale[4], lsum[4];
        #pragma unroll
        for (int i = 0; i < 4; i++) {
            float mnew = fmaxf(m_run[i], mtile[i]);
            pscale[i] = __expf(m_run[i] - mnew);
            m_run[i] = mnew;
            lsum[i] = 0.f;
        }
        #pragma unroll
        for (int cb = 0; cb < 4; cb++) {
            #pragma unroll
            for (int i = 0; i < 4; i++) {
                float mn = fmaxf(m_run[i], -1e20f);
                float p = __expf(sacc[cb][i] - mn);
                lsum[i] += p;
                int prow = (lane >> 4) * 4 + i;
                int pcol = cb * 16 + (lane & 15);
                int co = (pcol * 2) ^ ((prow & 7) << 4);
                *(f16*)((char*)&Ps[wave][prow][0] + co) = (f16)p;
            }
        }
        #pragma unroll
        for (int i = 0; i < 4; i++) {
            float v = lsum[i];
            v += __shfl_xor(v, 1);
            v += __shfl_xor(v, 2);
            v += __shfl_xor(v, 4);
            v += __shfl_xor(v, 8);
            l_run[i] = l_run[i] * pscale[i] + v;
        }
        #pragma unroll
        for (int db = 0; db < 8; db++)
            #pragma unroll
            for (int i = 0; i < 4; i++) oacc[db][i] *= pscale[i];
        __syncthreads();
        #pragma unroll
        for (int ks = 0; ks < 2; ks++) {
            int prow = lane & 15;
            int co = ((ks * 32 + (lane >> 4) * 8) * 2) ^ ((prow & 7) << 4);
            f16x8 pf = *(const f16x8*)((const char*)&Ps[wave][prow][0] + co);
            #pragma unroll
            for (int db = 0; db < 8; db++) {
                int vrow2 = db * 16 + (lane & 15);
                int co2 = ((ks * 32 + (lane >> 4) * 8) * 2) ^ ((vrow2 & 7) << 4);
                f16x8 vf = *(const f16x8*)((const char*)&VsT[vrow2][0] + co2);
                oacc[db] = MFMA16(pf, vf, oacc[db]);
            }
        }
    }
    #pragma unroll
    for (int db = 0; db < 8; db++) {
        #pragma unroll
        for (int i = 0; i < 4; i++) {
            int qi = qt + wave * 16 + (lane >> 4) * 4 + i;
            int d = db * 16 + (lane & 15);
            Og[(long)qi * D_ + head * HD_ + d] = (f16)(oacc[db][i] / l_run[i]);
        }
    }
}

// ------- Fused post-attention: x2 = x + p0 + p1; h2 = rms(x2)*ln2; router top-4 -------
__global__ __launch_bounds__(256) void postattn_kernel(
    const float* __restrict__ x, const float* __restrict__ p,
    const float* __restrict__ ln2, const float* __restrict__ wr,
    const float* __restrict__ wshg,
    float* __restrict__ x2, f16* __restrict__ h2,
    float* __restrict__ cw, float* __restrict__ sgate) {
    int t = blockIdx.x;
    int base = threadIdx.x * 8;
    long ro = (long)t * D_ + base;
    const long plane = (long)T_ * D_;
    float xv[8];
    #pragma unroll
    for (int j = 0; j < 8; j += 4) {
        float4 a = *(const float4*)(x + ro + j);
        float4 b = *(const float4*)(p + ro + j);
        float4 c = *(const float4*)(p + plane + ro + j);
        xv[j + 0] = a.x + b.x + c.x;
        xv[j + 1] = a.y + b.y + c.y;
        xv[j + 2] = a.z + b.z + c.z;
        xv[j + 3] = a.w + b.w + c.w;
    }
    *(float4*)(x2 + ro) = *(float4*)&xv[0];
    *(float4*)(x2 + ro + 4) = *(float4*)&xv[4];

    float ss = 0.f;
    #pragma unroll
    for (int j = 0; j < 8; j++) ss += xv[j] * xv[j];
    #pragma unroll
    for (int off = 1; off < 64; off <<= 1) ss += __shfl_xor(ss, off);
    __shared__ float red0[4];
    if ((threadIdx.x & 63) == 0) red0[threadIdx.x >> 6] = ss;
    __syncthreads();
    float scale = rsqrtf((red0[0] + red0[1] + red0[2] + red0[3]) / (float)D_ + 1e-6f);

    float part[9] = {0.f,0.f,0.f,0.f,0.f,0.f,0.f,0.f,0.f};
    f16x8 ho;
    #pragma unroll
    for (int j = 0; j < 8; j++) {
        int d = base + j;
        float hv = xv[j] * scale * ln2[d];
        ho[j] = (f16)hv;
        const float* wrow = wr + (long)d * E_;
        #pragma unroll
        for (int e = 0; e < 8; e++) part[e] += hv * wrow[e];
        part[8] += hv * wshg[d];
    }
    *(f16x8*)(h2 + ro) = ho;

    #pragma unroll
    for (int e = 0; e < 9; e++) {
        float v = part[e];
        #pragma unroll
        for (int off = 1; off < 64; off <<= 1) v += __shfl_xor(v, off);
        part[e] = v;
    }
    __shared__ float red[4][9];
    int lane = threadIdx.x & 63, wave = threadIdx.x >> 6;
    if (lane == 0)
        #pragma unroll
        for (int e = 0; e < 9; e++) red[wave][e] = part[e];
    __syncthreads();
    if (threadIdx.x == 0) {
        float logit[9];
        #pragma unroll
        for (int e = 0; e < 9; e++) logit[e] = red[0][e] + red[1][e] + red[2][e] + red[3][e];
        float mx = logit[0];
        #pragma unroll
        for (int e = 1; e < 8; e++) mx = fmaxf(mx, logit[e]);
        float pp[8], sum = 0.f;
        #pragma unroll
        for (int e = 0; e < 8; e++) { pp[e] = expf(logit[e] - mx); sum += pp[e]; }
        #pragma unroll
        for (int e = 0; e < 8; e++) pp[e] /= sum;
        float sel[8] = {0.f,0.f,0.f,0.f,0.f,0.f,0.f,0.f};
        float tmp[8];
        #pragma unroll
        for (int e = 0; e < 8; e++) tmp[e] = pp[e];
        for (int it = 0; it < 4; it++) {
            int best = 0;
            float bvv = tmp[0];
            #pragma unroll
            for (int e = 1; e < 8; e++)
                if (tmp[e] > bvv) { bvv = tmp[e]; best = e; }
            sel[best] = pp[best];
            tmp[best] = -1.f;
        }
        #pragma unroll
        for (int e = 0; e < 8; e++) cw[(long)e * T_ + t] = sel[e];
        sgate[t] = 1.f / (1.f + expf(-logit[8]));
    }
}

// ---------------- deterministic expert bucketing (1 block, 8 waves) ----------------
__global__ __launch_bounds__(512) void bucket_kernel(const float* __restrict__ cw,
                                                     int* __restrict__ cnt,
                                                     int* __restrict__ tokidx,
                                                     float* __restrict__ tw,
                                                     int* __restrict__ posmat) {
    int e = threadIdx.x >> 6, lane = threadIdx.x & 63;
    int count = 0;
    for (int base = 0; base < T_; base += 64) {
        int t = base + lane;
        float wv = cw[(long)e * T_ + t];
        unsigned long long m = __ballot(wv > 0.f);
        int pre = __popcll(m & ((1ull << lane) - 1ull));
        if (wv > 0.f) {
            int s = count + pre;
            tokidx[e * T_ + s] = t;
            tw[e * T_ + s] = wv;
            posmat[e * T_ + t] = s;
        }
        count += __popcll(m);
    }
    if (lane == 0) cnt[e] = count;
}

// ---------------- bias concat ----------------
__global__ __launch_bounds__(256) void biascat_kernel(const float* bq, const float* bk,
                                                      const float* bv, float* bqkv) {
    int i = blockIdx.x * 256 + threadIdx.x;
    if (i < 2048) bqkv[i] = bq[i];
    else if (i < 4096) bqkv[i] = bk[i - 2048];
    else if (i < 6144) bqkv[i] = bv[i - 4096];
}

// ---------------- split-K reduce: out = p0+p1+p2+p3 ----------------
__global__ __launch_bounds__(256) void reduce4_kernel(const float* __restrict__ p,
                                                      float* __restrict__ out) {
    long total = (long)T_ * D_ / 4;
    for (long i = (long)blockIdx.x * 256 + threadIdx.x; i < total;
         i += (long)gridDim.x * 256) {
        float4 a = ((const float4*)p)[i];
        float4 b = ((const float4*)p)[i + total];
        float4 c = ((const float4*)p)[i + 2 * total];
        float4 d = ((const float4*)p)[i + 3 * total];
        float4 o;
        o.x = a.x + b.x + c.x + d.x; o.y = a.y + b.y + c.y + d.y;
        o.z = a.z + b.z + c.z + d.z; o.w = a.w + b.w + c.w + d.w;
        ((float4*)out)[i] = o;
    }
}

// ---------------- Final combine: out = x2 + sum_e eo[e][slot] (pre-weighted) + sg*sho --
__global__ __launch_bounds__(256) void combine_kernel(
    const float* __restrict__ x2, const float* __restrict__ sho,
    const float* __restrict__ sg, const float* __restrict__ cw,
    const int* __restrict__ posmat, const f16* __restrict__ eo,
    float* __restrict__ out) {
    long total = (long)T_ * D_ / 4;
    for (long i = (long)blockIdx.x * 256 + threadIdx.x; i < total;
         i += (long)gridDim.x * 256) {
        int t = (int)(i >> 9);
        int c4 = (int)(i & 511) * 4;
        float4 a = ((const float4*)x2)[i];
        float4 s = ((const float4*)sho)[i];
        float g = sg[t];
        float r0 = a.x + g * s.x, r1 = a.y + g * s.y;
        float r2 = a.z + g * s.z, r3 = a.w + g * s.w;
        #pragma unroll
        for (int e = 0; e < 8; e++) {
            float w = cw[(long)e * T_ + t];
            if (w > 0.f) {
                int slot = posmat[(long)e * T_ + t];
                f16x4 v = *(const f16x4*)(eo + ((long)e * T_ + slot) * D_ + c4);
                r0 += (float)v[0]; r1 += (float)v[1];
                r2 += (float)v[2]; r3 += (float)v[3];
            }
        }
        float4 o; o.x = r0; o.y = r1; o.z = r2; o.w = r3;
        ((float4*)out)[i] = o;
    }
}

extern "C" void kernel_launch(void* const* d_in, const int* in_sizes, int n_in,
                              void* d_out, int out_size, void* d_ws, size_t ws_size,
                              hipStream_t stream) {
    const float* x    = (const float*)d_in[0];
    const float* ln1  = (const float*)d_in[1];
    const float* ln2  = (const float*)d_in[2];
    const float* wq   = (const float*)d_in[3];
    const float* bq   = (const float*)d_in[4];
    const float* wk   = (const float*)d_in[5];
    const float* bk   = (const float*)d_in[6];
    const float* wv   = (const float*)d_in[7];
    const float* bv   = (const float*)d_in[8];
    const float* wo   = (const float*)d_in[9];
    const float* wrt  = (const float*)d_in[10];
    const float* wge  = (const float*)d_in[11];
    const float* wue  = (const float*)d_in[12];
    const float* wde  = (const float*)d_in[13];
    const float* wsg  = (const float*)d_in[14];
    const float* wsu  = (const float*)d_in[15];
    const float* wsd  = (const float*)d_in[16];
    const float* wshg = (const float*)d_in[17];

    float* ws = (float*)d_ws;
    f16*   wT     = (f16*)ws;                       // 11,534,336 floats
    float* x2     = ws + 11534336;                  // 2,097,152
    float* sho    = x2 + 2097152;                   // 2,097,152
    float* bqkv   = sho + 2097152;                  // 6,144
    float* cw     = bqkv + 6144;                    // 8,192
    float* sg     = cw + 8192;                      // 1,024
    int*   cnt    = (int*)(sg + 1024);              // 8
    int*   tokidx = cnt + 8;                        // 8,192
    float* tw     = (float*)(tokidx + 8192);        // 8,192
    int*   posmat = (int*)(tw + 8192);              // 8,192
    f16*   h1     = (f16*)(posmat + 8192);          // 1,048,576 floats
    f16*   h2     = (f16*)((float*)h1 + 1048576);   // 1,048,576 floats
    float* pool   = (float*)h2 + 1048576;           // 14,155,776 floats

    // pool phase aliases
    f16*   qkv     = (f16*)pool;                    // 3,145,728 floats
    float* woparts = pool + 3145728;                // 4,194,304 floats (2 planes)
    f16*   sgb     = (f16*)pool;                    // 2,883,584 floats
    float* parts4  = pool + 2883584;                // 8,388,608 floats (4 planes)
    f16*   Gg      = (f16*)pool;                    // 5,767,168 floats
    f16*   eo      = (f16*)(pool + 5767168);        // 8,388,608 floats
    f16*   ao      = h1;                            // alias (h1 dead after QKV GEMM)

    dim3 blk(256);

    // ---- attention block ----
    rmsnorm16_kernel<<<T_, blk, 0, stream>>>(x, ln1, h1);
    biascat_kernel<<<24, blk, 0, stream>>>(bq, bk, bv, bqkv);
    tconv_kernel<<<dim3(32, 32, 1), blk, 0, stream>>>(wq, wT, 2048, 2048, 0, 0);
    tconv_kernel<<<dim3(32, 32, 1), blk, 0, stream>>>(wk, wT + 2048L * 2048, 2048, 2048, 0, 0);
    tconv_kernel<<<dim3(32, 32, 1), blk, 0, stream>>>(wv, wT + 4096L * 2048, 2048, 2048, 0, 0);
    gemm16_kernel<1, 0><<<dim3(48, 8, 1), blk, 0, stream>>>(
        h1, wT, qkv, bqkv, nullptr, nullptr, nullptr,
        T_, QKVN, D_, 2048, 2048, 0, 0, 0);
    rope16_kernel<<<S_, blk, 0, stream>>>(qkv);
    attn16_kernel<<<dim3(16, 16), blk, 0, stream>>>(qkv, ao);
    tconv_kernel<<<dim3(32, 32, 1), blk, 0, stream>>>(wo, wT, 2048, 2048, 0, 0);
    // wo GEMM split-K=2 -> fp32 partials
    gemm16_kernel<4, 0><<<dim3(16, 8, 2), blk, 0, stream>>>(
        ao, wT, woparts, nullptr, nullptr, nullptr, nullptr,
        T_, D_, 1024, 2048, 2048, 1024, 1024, 2097152);
    // fused: x2 = x + p0 + p1; h2 = rms(x2); router top-4 + shared gate
    postattn_kernel<<<T_, blk, 0, stream>>>(x, woparts, ln2, wrt, wshg, x2, h2, cw, sg);
    bucket_kernel<<<1, 512, 0, stream>>>(cw, cnt, tokidx, tw, posmat);

    // shared expert: fused gate+up (one dual-source tconv), then split-K=4 down
    tconv_gu_kernel<<<dim3(88, 32, 2), blk, 0, stream>>>(wsg, wsu, wT, 2048, 5632, 0, 0, 1);
    gemm16_kernel<5, 0><<<dim3(88, 8, 1), blk, 0, stream>>>(
        h2, wT, sgb, nullptr, nullptr, nullptr, nullptr,
        T_, 2 * FS_, D_, 2048, 2048, 0, 0, 0);
    tconv_kernel<<<dim3(32, 88, 1), blk, 0, stream>>>(wsd, wT, 5632, 2048, 0, 0);
    gemm16_kernel<4, 0><<<dim3(16, 8, 4), blk, 0, stream>>>(
        sgb, wT, parts4, nullptr, nullptr, nullptr, nullptr,
        T_, D_, 1408, 5632, 5632, 1408, 1408, 2097152);
    reduce4_kernel<<<512, blk, 0, stream>>>(parts4, sho);

    // routed experts (top-4 sparse), batch 1 (e0-3): dual-source gate+up tconv
    tconv_gu_kernel<<<dim3(22, 32, 8), blk, 0, stream>>>(
        wge, wue, wT, 2048, 1408, 2048L * 1408, 2816L * 2048, 4);
    gemm16_kernel<5, 1><<<dim3(22, 8, 4), blk, 0, stream>>>(
        h2, wT, Gg, nullptr, tokidx, cnt, nullptr,
        T_, 2 * FI_, D_, 2048, 2048, 0, 2816L * 2048, 1024L * 1408);
    // batch 2 (e4-7)
    tconv_gu_kernel<<<dim3(22, 32, 8), blk, 0, stream>>>(
        wge + 4L * 2048 * 1408, wue + 4L * 2048 * 1408, wT, 2048, 1408,
        2048L * 1408, 2816L * 2048, 4);
    gemm16_kernel<5, 1><<<dim3(22, 8, 4), blk, 0, stream>>>(
        h2, wT, Gg + 4L * 1024 * 1408, nullptr, tokidx + 4 * T_, cnt + 4, nullptr,
        T_, 2 * FI_, D_, 2048, 2048, 0, 2816L * 2048, 1024L * 1408);

    // down: all 8 experts in one tconv + one GEMM (wT holds 8 x 2048x1408 f16 exactly)
    tconv_kernel<<<dim3(32, 22, 8), blk, 0, stream>>>(wde, wT, 1408, 2048,
                                                      1408L * 2048, 2048L * 1408);
    gemm16_kernel<6, 2><<<dim3(16, 8, 8), blk, 0, stream>>>(
        Gg, wT, eo, nullptr, nullptr, cnt, tw,
        T_, D_, 1408, 1408, 1408, 1024L * 1408, 2048L * 1408, 1024L * 2048);

    combine_kernel<<<1024, blk, 0, stream>>>(x2, sho, sg, cw, posmat, eo, (float*)d_out);
}

// Round 9
// 555.198 us; speedup vs baseline: 1.0515x; 1.0515x over previous
//
#include <hip/hip_runtime.h>

#define S_ 1024
#define D_ 2048
#define H_ 16
#define HD_ 128
#define E_ 8
#define FI_ 1408
#define FS_ 5632
#define WIN_ 512
#define T_ 1024
#define QKVN 6144

typedef _Float16 f16;
typedef __attribute__((ext_vector_type(8))) _Float16 f16x8;
typedef __attribute__((ext_vector_type(4))) _Float16 f16x4;
typedef __attribute__((ext_vector_type(4))) float f32x4;

#define MFMA16(a, b, c) __builtin_amdgcn_mfma_f32_16x16x32_f16((a), (b), (c), 0, 0, 0)

__device__ __forceinline__ void gload16(const void* g, void* l) {
    __builtin_amdgcn_global_load_lds(
        (const __attribute__((address_space(1))) unsigned*)g,
        (__attribute__((address_space(3))) unsigned*)l, 16, 0, 0);
}

// ---------------- RMSNorm (fp32 in -> f16 out) ----------------
__global__ __launch_bounds__(256) void rmsnorm16_kernel(const float* __restrict__ x,
                                                        const float* __restrict__ w,
                                                        f16* __restrict__ out) {
    int t = blockIdx.x;
    const float* xr = x + (long)t * D_;
    int base = threadIdx.x * 8;
    float4 v0 = *(const float4*)(xr + base);
    float4 v1 = *(const float4*)(xr + base + 4);
    float ss = v0.x*v0.x + v0.y*v0.y + v0.z*v0.z + v0.w*v0.w
             + v1.x*v1.x + v1.y*v1.y + v1.z*v1.z + v1.w*v1.w;
    #pragma unroll
    for (int off = 1; off < 64; off <<= 1) ss += __shfl_xor(ss, off);
    __shared__ float red[4];
    if ((threadIdx.x & 63) == 0) red[threadIdx.x >> 6] = ss;
    __syncthreads();
    float tot = red[0] + red[1] + red[2] + red[3];
    float scale = rsqrtf(tot / (float)D_ + 1e-6f);
    float4 w0 = *(const float4*)(w + base);
    float4 w1 = *(const float4*)(w + base + 4);
    f16x8 o;
    o[0] = (f16)(v0.x*scale*w0.x); o[1] = (f16)(v0.y*scale*w0.y);
    o[2] = (f16)(v0.z*scale*w0.z); o[3] = (f16)(v0.w*scale*w0.w);
    o[4] = (f16)(v1.x*scale*w1.x); o[5] = (f16)(v1.y*scale*w1.y);
    o[6] = (f16)(v1.z*scale*w1.z); o[7] = (f16)(v1.w*scale*w1.w);
    *(f16x8*)(out + (long)t * D_ + base) = o;
}

// ---------------- Transpose+convert: W[K][N] fp32 -> WT f16, vector stores ----------
// mode 0: dst row = n; mode 1 (gate-interleave): row = (n>>4)*32 + (n&15);
// mode 2 (up-interleave): row = (n>>4)*32 + 16 + (n&15)
__device__ __forceinline__ void tconv_body(const float* __restrict__ src,
                                           f16* __restrict__ dst,
                                           int K, int N, int mode) {
    int n0 = blockIdx.x * 64, k0 = blockIdx.y * 64;
    __shared__ f16 tile[64][72];  // [n][k]
    int t = threadIdx.x, r = t >> 2, c4 = (t & 3) * 16;
    const float* sp = src + (long)(k0 + r) * N + n0 + c4;
    #pragma unroll
    for (int i = 0; i < 16; i += 4) {
        float4 v = *(const float4*)(sp + i);
        tile[c4 + i + 0][r] = (f16)v.x;
        tile[c4 + i + 1][r] = (f16)v.y;
        tile[c4 + i + 2][r] = (f16)v.z;
        tile[c4 + i + 3][r] = (f16)v.w;
    }
    __syncthreads();
    #pragma unroll
    for (int h = 0; h < 2; h++) {
        int v = t + h * 256;
        int nl = v >> 3, c8 = (v & 7) * 8;
        f16x8 vec = *(const f16x8*)&tile[nl][c8];
        int nr = n0 + nl;
        long orow = (mode == 0) ? nr
                  : ((long)(nr >> 4) * 32 + (nr & 15) + (mode == 2 ? 16 : 0));
        *(f16x8*)(dst + orow * K + k0 + c8) = vec;
    }
}

__global__ __launch_bounds__(256) void tconv_kernel(const float* __restrict__ src,
                                                    f16* __restrict__ dst,
                                                    int K, int N, long sSrc, long sDst) {
    tconv_body(src + (long)blockIdx.z * sSrc, dst + (long)blockIdx.z * sDst, K, N, 0);
}

// all 4 attention weights in one launch (z: 0=q,1=k,2=v,3=o)
__global__ __launch_bounds__(256) void tconv_qkvo_kernel(const float* __restrict__ wq,
                                                         const float* __restrict__ wk,
                                                         const float* __restrict__ wv,
                                                         const float* __restrict__ wo,
                                                         f16* __restrict__ dst) {
    int z = blockIdx.z;
    const float* src = (z == 0) ? wq : (z == 1) ? wk : (z == 2) ? wv : wo;
    tconv_body(src, dst + (long)z * 2048 * 2048, 2048, 2048, 0);
}

// gate+up combined: z < zsplit -> srcA/mode1/e=z ; else srcB/mode2/e=z-zsplit
__global__ __launch_bounds__(256) void tconv_gu_kernel(const float* __restrict__ srcA,
                                                       const float* __restrict__ srcB,
                                                       f16* __restrict__ dst,
                                                       int K, int N, long sSrc, long sDst,
                                                       int zsplit) {
    int z = blockIdx.z;
    int e = (z < zsplit) ? z : z - zsplit;
    const float* src = ((z < zsplit) ? srcA : srcB) + (long)e * sSrc;
    tconv_body(src, dst + (long)e * sDst, K, N, (z < zsplit) ? 1 : 2);
}

// ---------------- GEMM f16: C = A @ BT^T, swizzled LDS, XCD block swizzle -----------
// EPI: 1 = f16 out + bias_f32[n]; 4 = f32 partial out (plane z);
//      5 = fused silu-pair f16; 6 = f16 out scaled by tw[z*T+m]
// MODE: 0 = normal; 1 = gather A rows via tokidx + early-exit; 2 = early-exit only
template <int EPI, int MODE>
__global__ __launch_bounds__(256) void gemm16_kernel(
    const f16* __restrict__ Ag, const f16* __restrict__ BTg,
    void* Cg, const void* auxg,
    const int* __restrict__ tokidx, const int* __restrict__ cntv,
    const float* __restrict__ tw,
    int M, int N, int K, int lda, int ldb,
    long sA, long sB, long sC) {
    int z = blockIdx.z;
    const f16* A = Ag + (long)z * sA;
    const f16* BT = BTg + (long)z * sB;

    // XCD-chunked bijective swizzle (nwg % 8 == 0 for all our grids), by-fastest:
    // each XCD's contiguous chunk iterates M-blocks first -> B panel reuse in its L2.
    int nxy = gridDim.x * gridDim.y;
    int pid = blockIdx.y * gridDim.x + blockIdx.x;
    if ((nxy & 7) == 0) pid = (pid & 7) * (nxy >> 3) + (pid >> 3);
    int bx = pid / gridDim.y, by = pid % gridDim.y;
    int bm = by * 128, bn = bx * 128;

    int cnt = M;
    if (MODE >= 1) {
        cnt = cntv[z];
        if (bm >= cnt) return;
    }
    int tid = threadIdx.x, lane = tid & 63, wave = tid >> 6;
    int wm = (wave >> 1) * 64, wn = (wave & 1) * 64;

    __shared__ f16 As[128][64];
    __shared__ f16 Bs[128][64];

    f32x4 acc[4][4];
    #pragma unroll
    for (int i = 0; i < 4; i++)
        #pragma unroll
        for (int j = 0; j < 4; j++) acc[i][j] = (f32x4){0.f, 0.f, 0.f, 0.f};

    int srow8 = lane >> 3;
    int scol = ((lane & 7) ^ srow8) * 8;   // pre-swizzled global source
    const f16* Abp[4];
    const f16* Bbp[4];
    #pragma unroll
    for (int i = 0; i < 4; i++) {
        int ra = bm + wave * 32 + i * 8 + srow8;
        long arow;
        if (MODE == 1) {
            int tok = (ra < cnt) ? tokidx[z * T_ + ra] : 0;
            arow = tok;
        } else {
            arow = ra;
        }
        Abp[i] = A + arow * (long)lda + scol;
        Bbp[i] = BT + (long)(bn + wave * 32 + i * 8 + srow8) * ldb + scol;
    }

    for (int k0 = 0; k0 < K; k0 += 64) {
        __syncthreads();
        #pragma unroll
        for (int i = 0; i < 4; i++) {
            gload16(Abp[i] + k0, &As[wave * 32 + i * 8][0]);
            gload16(Bbp[i] + k0, &Bs[wave * 32 + i * 8][0]);
        }
        __syncthreads();
        #pragma unroll
        for (int kk = 0; kk < 64; kk += 32) {
            f16x8 af[4], bf[4];
            #pragma unroll
            for (int mi = 0; mi < 4; mi++) {
                int r = wm + mi * 16 + (lane & 15);
                int c = ((kk >> 3) + (lane >> 4)) ^ (r & 7);
                af[mi] = *(const f16x8*)((const char*)&As[r][0] + (c << 4));
            }
            #pragma unroll
            for (int ni = 0; ni < 4; ni++) {
                int r = wn + ni * 16 + (lane & 15);
                int c = ((kk >> 3) + (lane >> 4)) ^ (r & 7);
                bf[ni] = *(const f16x8*)((const char*)&Bs[r][0] + (c << 4));
            }
            #pragma unroll
            for (int mi = 0; mi < 4; mi++)
                #pragma unroll
                for (int ni = 0; ni < 4; ni++)
                    acc[mi][ni] = MFMA16(af[mi], bf[ni], acc[mi][ni]);
        }
    }

    if (EPI == 5) {
        int half = N >> 1;
        #pragma unroll
        for (int mi = 0; mi < 4; mi++) {
            #pragma unroll
            for (int p = 0; p < 2; p++) {
                #pragma unroll
                for (int i = 0; i < 4; i++) {
                    int m = bm + wm + mi * 16 + (lane >> 4) * 4 + i;
                    int j = ((bn + wn) >> 1) + p * 16 + (lane & 15);
                    float g = acc[mi][2 * p][i];
                    float u = acc[mi][2 * p + 1][i];
                    ((f16*)Cg + (long)z * sC)[(long)m * half + j] =
                        (f16)(g / (1.f + __expf(-g)) * u);
                }
            }
        }
        return;
    }
    #pragma unroll
    for (int mi = 0; mi < 4; mi++) {
        #pragma unroll
        for (int ni = 0; ni < 4; ni++) {
            #pragma unroll
            for (int i = 0; i < 4; i++) {
                int m = bm + wm + mi * 16 + (lane >> 4) * 4 + i;
                int n = bn + wn + ni * 16 + (lane & 15);
                long idx = (long)m * N + n;
                float v = acc[mi][ni][i];
                if (EPI == 1) {
                    ((f16*)Cg)[idx] = (f16)(v + ((const float*)auxg)[n]);
                } else if (EPI == 4) {
                    ((float*)Cg + (long)z * sC)[idx] = v;
                } else if (EPI == 6) {
                    float wv = tw[z * T_ + m];
                    ((f16*)Cg + (long)z * sC)[idx] = (f16)(v * wv);
                }
            }
        }
    }
}

// ---------------- RoPE in-place on f16 qkv ----------------
__global__ __launch_bounds__(256) void rope16_kernel(f16* __restrict__ qkv) {
    int s = blockIdx.x;
    float fs = (float)s;
    for (int p = threadIdx.x; p < H_ * 64; p += 256) {
        int h = p >> 6, j = p & 63;
        float inv = __expf(-(float)j * (13.815510557964274f / 64.f));  // 1e6^(-j/64)
        float ang = fs * inv;
        float c = cosf(ang), sn = sinf(ang);
        long base = (long)s * QKVN + h * HD_ + j;
        float q1 = (float)qkv[base], q2 = (float)qkv[base + 64];
        qkv[base] = (f16)(q1 * c - q2 * sn);
        qkv[base + 64] = (f16)(q2 * c + q1 * sn);
        long kb = base + 2048;
        float k1 = (float)qkv[kb], k2 = (float)qkv[kb + 64];
        qkv[kb] = (f16)(k1 * c - k2 * sn);
        qkv[kb + 64] = (f16)(k2 * c + k1 * sn);
    }
}

// ---------------- Sliding-window flash attention (f16) ----------------
__global__ __launch_bounds__(256) void attn16_kernel(const f16* __restrict__ qkv,
                                                     f16* __restrict__ Og) {
    int qt = blockIdx.x * 64;
    int head = blockIdx.y;
    int tid = threadIdx.x, lane = tid & 63, wave = tid >> 6;

    __shared__ f16 Ks[64][128];
    __shared__ f16 Vrow[64][128];
    __shared__ f16 VsT[128][64];
    __shared__ f16 Ps[4][16][64];

    int qr = qt + wave * 16 + (lane & 15);
    const f16* Qp = qkv + (long)qr * QKVN + head * HD_;
    f16x8 qf[4];
    #pragma unroll
    for (int kk = 0; kk < 4; kk++)
        qf[kk] = *(const f16x8*)(Qp + kk * 32 + (lane >> 4) * 8);

    f32x4 oacc[8];
    #pragma unroll
    for (int db = 0; db < 8; db++) oacc[db] = (f32x4){0.f, 0.f, 0.f, 0.f};
    float m_run[4] = {-1e30f, -1e30f, -1e30f, -1e30f};
    float l_run[4] = {0.f, 0.f, 0.f, 0.f};

    int k_lo = qt - (WIN_ - 1);
    if (k_lo < 0) k_lo = 0;
    k_lo &= ~63;

    for (int k0 = k_lo; k0 < qt + 64; k0 += 64) {
        __syncthreads();
        {
            int row = tid >> 2, cq = (tid & 3) * 32;
            const f16* Kp = qkv + (long)(k0 + row) * QKVN + 2048 + head * HD_ + cq;
            const f16* Vp = Kp + 2048;
            #pragma unroll
            for (int u = 0; u < 32; u += 8) {
                f16x8 tk = *(const f16x8*)(Kp + u);
                int co = ((cq + u) * 2) ^ ((row & 7) << 4);
                *(f16x8*)((char*)&Ks[row][0] + co) = tk;
                *(f16x8*)(&Vrow[row][cq + u]) = *(const f16x8*)(Vp + u);
            }
        }
        __syncthreads();
        {
            int d = tid >> 1, ks = (tid & 1) * 32;
            f16 tmp[32];
            #pragma unroll
            for (int j = 0; j < 32; j++) tmp[j] = Vrow[ks + j][d];
            #pragma unroll
            for (int u = 0; u < 32; u += 8) {
                int co = ((ks + u) * 2) ^ ((d & 7) << 4);
                f16x8 tv;
                #pragma unroll
                for (int j = 0; j < 8; j++) tv[j] = tmp[u + j];
                *(f16x8*)((char*)&VsT[d][0] + co) = tv;
            }
        }
        f32x4 sacc[4];
        #pragma unroll
        for (int cb = 0; cb < 4; cb++) sacc[cb] = (f32x4){0.f, 0.f, 0.f, 0.f};
        __builtin_amdgcn_s_setprio(1);
        #pragma unroll
        for (int kk = 0; kk < 4; kk++) {
            #pragma unroll
            for (int cb = 0; cb < 4; cb++) {
                int krow = cb * 16 + (lane & 15);
                int co = ((kk * 32 + (lane >> 4) * 8) * 2) ^ ((krow & 7) << 4);
                f16x8 kf = *(const f16x8*)((const char*)&Ks[krow][0] + co);
                sacc[cb] = MFMA16(qf[kk], kf, sacc[cb]);
            }
        }
        __builtin_amdgcn_s_setprio(0);
        float mtile[4] = {-1e30f, -1e30f, -1e30f, -1e30f};
        #pragma unroll
        for (int cb = 0; cb < 4; cb++) {
            #pragma unroll
            for (int i = 0; i < 4; i++) {
                int qi = qt + wave * 16 + (lane >> 4) * 4 + i;
                int kj = k0 + cb * 16 + (lane & 15);
                float s = sacc[cb][i] * 0.08838834764831845f;
                bool valid = (kj <= qi) && (qi - kj < WIN_);
                s = valid ? s : -1e30f;
                sacc[cb][i] = s;
                mtile[i] = fmaxf(mtile[i], s);
            }
        }
        #pragma unroll
        for (int i = 0; i < 4; i++) {
            float v = mtile[i];
            v = fmaxf(v, __shfl_xor(v, 1));
            v = fmaxf(v, __shfl_xor(v, 2));
            v = fmaxf(v, __shfl_xor(v, 4));
            v = fmaxf(v, __shfl_xor(v, 8));
            mtile[i] = v;
        }
        float pscale[4], lsum[4];
        #pragma unroll
        for (int i = 0; i < 4; i++) {
            float mnew = fmaxf(m_run[i], mtile[i]);
            pscale[i] = __expf(m_run[i] - mnew);
            m_run[i] = mnew;
            lsum[i] = 0.f;
        }
        #pragma unroll
        for (int cb = 0; cb < 4; cb++) {
            #pragma unroll
            for (int i = 0; i < 4; i++) {
                float mn = fmaxf(m_run[i], -1e20f);
                float p = __expf(sacc[cb][i] - mn);
                lsum[i] += p;
                int prow = (lane >> 4) * 4 + i;
                int pcol = cb * 16 + (lane & 15);
                int co = (pcol * 2) ^ ((prow & 7) << 4);
                *(f16*)((char*)&Ps[wave][prow][0] + co) = (f16)p;
            }
        }
        #pragma unroll
        for (int i = 0; i < 4; i++) {
            float v = lsum[i];
            v += __shfl_xor(v, 1);
            v += __shfl_xor(v, 2);
            v += __shfl_xor(v, 4);
            v += __shfl_xor(v, 8);
            l_run[i] = l_run[i] * pscale[i] + v;
        }
        #pragma unroll
        for (int db = 0; db < 8; db++)
            #pragma unroll
            for (int i = 0; i < 4; i++) oacc[db][i] *= pscale[i];
        __syncthreads();
        __builtin_amdgcn_s_setprio(1);
        #pragma unroll
        for (int ks = 0; ks < 2; ks++) {
            int prow = lane & 15;
            int co = ((ks * 32 + (lane >> 4) * 8) * 2) ^ ((prow & 7) << 4);
            f16x8 pf = *(const f16x8*)((const char*)&Ps[wave][prow][0] + co);
            #pragma unroll
            for (int db = 0; db < 8; db++) {
                int vrow2 = db * 16 + (lane & 15);
                int co2 = ((ks * 32 + (lane >> 4) * 8) * 2) ^ ((vrow2 & 7) << 4);
                f16x8 vf = *(const f16x8*)((const char*)&VsT[vrow2][0] + co2);
                oacc[db] = MFMA16(pf, vf, oacc[db]);
            }
        }
        __builtin_amdgcn_s_setprio(0);
    }
    #pragma unroll
    for (int db = 0; db < 8; db++) {
        #pragma unroll
        for (int i = 0; i < 4; i++) {
            int qi = qt + wave * 16 + (lane >> 4) * 4 + i;
            int d = db * 16 + (lane & 15);
            Og[(long)qi * D_ + head * HD_ + d] = (f16)(oacc[db][i] / l_run[i]);
        }
    }
}

// ------- Fused post-attention: x2 = x + p0 + p1; h2 = rms(x2)*ln2; router top-4 -------
__global__ __launch_bounds__(256) void postattn_kernel(
    const float* __restrict__ x, const float* __restrict__ p,
    const float* __restrict__ ln2, const float* __restrict__ wr,
    const float* __restrict__ wshg,
    float* __restrict__ x2, f16* __restrict__ h2,
    float* __restrict__ cw, float* __restrict__ sgate) {
    int t = blockIdx.x;
    int base = threadIdx.x * 8;
    long ro = (long)t * D_ + base;
    const long plane = (long)T_ * D_;
    float xv[8];
    #pragma unroll
    for (int j = 0; j < 8; j += 4) {
        float4 a = *(const float4*)(x + ro + j);
        float4 b = *(const float4*)(p + ro + j);
        float4 c = *(const float4*)(p + plane + ro + j);
        xv[j + 0] = a.x + b.x + c.x;
        xv[j + 1] = a.y + b.y + c.y;
        xv[j + 2] = a.z + b.z + c.z;
        xv[j + 3] = a.w + b.w + c.w;
    }
    *(float4*)(x2 + ro) = *(float4*)&xv[0];
    *(float4*)(x2 + ro + 4) = *(float4*)&xv[4];

    float ss = 0.f;
    #pragma unroll
    for (int j = 0; j < 8; j++) ss += xv[j] * xv[j];
    #pragma unroll
    for (int off = 1; off < 64; off <<= 1) ss += __shfl_xor(ss, off);
    __shared__ float red0[4];
    if ((threadIdx.x & 63) == 0) red0[threadIdx.x >> 6] = ss;
    __syncthreads();
    float scale = rsqrtf((red0[0] + red0[1] + red0[2] + red0[3]) / (float)D_ + 1e-6f);

    float part[9] = {0.f,0.f,0.f,0.f,0.f,0.f,0.f,0.f,0.f};
    f16x8 ho;
    #pragma unroll
    for (int j = 0; j < 8; j++) {
        int d = base + j;
        float hv = xv[j] * scale * ln2[d];
        ho[j] = (f16)hv;
        const float* wrow = wr + (long)d * E_;
        #pragma unroll
        for (int e = 0; e < 8; e++) part[e] += hv * wrow[e];
        part[8] += hv * wshg[d];
    }
    *(f16x8*)(h2 + ro) = ho;

    #pragma unroll
    for (int e = 0; e < 9; e++) {
        float v = part[e];
        #pragma unroll
        for (int off = 1; off < 64; off <<= 1) v += __shfl_xor(v, off);
        part[e] = v;
    }
    __shared__ float red[4][9];
    int lane = threadIdx.x & 63, wave = threadIdx.x >> 6;
    if (lane == 0)
        #pragma unroll
        for (int e = 0; e < 9; e++) red[wave][e] = part[e];
    __syncthreads();
    if (threadIdx.x == 0) {
        float logit[9];
        #pragma unroll
        for (int e = 0; e < 9; e++) logit[e] = red[0][e] + red[1][e] + red[2][e] + red[3][e];
        float mx = logit[0];
        #pragma unroll
        for (int e = 1; e < 8; e++) mx = fmaxf(mx, logit[e]);
        float pp[8], sum = 0.f;
        #pragma unroll
        for (int e = 0; e < 8; e++) { pp[e] = expf(logit[e] - mx); sum += pp[e]; }
        #pragma unroll
        for (int e = 0; e < 8; e++) pp[e] /= sum;
        float sel[8] = {0.f,0.f,0.f,0.f,0.f,0.f,0.f,0.f};
        float tmp[8];
        #pragma unroll
        for (int e = 0; e < 8; e++) tmp[e] = pp[e];
        for (int it = 0; it < 4; it++) {
            int best = 0;
            float bvv = tmp[0];
            #pragma unroll
            for (int e = 1; e < 8; e++)
                if (tmp[e] > bvv) { bvv = tmp[e]; best = e; }
            sel[best] = pp[best];
            tmp[best] = -1.f;
        }
        #pragma unroll
        for (int e = 0; e < 8; e++) cw[(long)e * T_ + t] = sel[e];
        sgate[t] = 1.f / (1.f + expf(-logit[8]));
    }
}

// ---------------- deterministic expert bucketing (1 block, 8 waves) ----------------
__global__ __launch_bounds__(512) void bucket_kernel(const float* __restrict__ cw,
                                                     int* __restrict__ cnt,
                                                     int* __restrict__ tokidx,
                                                     float* __restrict__ tw,
                                                     int* __restrict__ posmat) {
    int e = threadIdx.x >> 6, lane = threadIdx.x & 63;
    int count = 0;
    for (int base = 0; base < T_; base += 64) {
        int t = base + lane;
        float wv = cw[(long)e * T_ + t];
        unsigned long long m = __ballot(wv > 0.f);
        int pre = __popcll(m & ((1ull << lane) - 1ull));
        if (wv > 0.f) {
            int s = count + pre;
            tokidx[e * T_ + s] = t;
            tw[e * T_ + s] = wv;
            posmat[e * T_ + t] = s;
        }
        count += __popcll(m);
    }
    if (lane == 0) cnt[e] = count;
}

// ---------------- bias concat ----------------
__global__ __launch_bounds__(256) void biascat_kernel(const float* bq, const float* bk,
                                                      const float* bv, float* bqkv) {
    int i = blockIdx.x * 256 + threadIdx.x;
    if (i < 2048) bqkv[i] = bq[i];
    else if (i < 4096) bqkv[i] = bk[i - 2048];
    else if (i < 6144) bqkv[i] = bv[i - 4096];
}

// ---------------- split-K reduce: out = p0+p1+p2+p3 ----------------
__global__ __launch_bounds__(256) void reduce4_kernel(const float* __restrict__ p,
                                                      float* __restrict__ out) {
    long total = (long)T_ * D_ / 4;
    for (long i = (long)blockIdx.x * 256 + threadIdx.x; i < total;
         i += (long)gridDim.x * 256) {
        float4 a = ((const float4*)p)[i];
        float4 b = ((const float4*)p)[i + total];
        float4 c = ((const float4*)p)[i + 2 * total];
        float4 d = ((const float4*)p)[i + 3 * total];
        float4 o;
        o.x = a.x + b.x + c.x + d.x; o.y = a.y + b.y + c.y + d.y;
        o.z = a.z + b.z + c.z + d.z; o.w = a.w + b.w + c.w + d.w;
        ((float4*)out)[i] = o;
    }
}

// ---------------- Final combine: out = x2 + sum_e eo[e][slot] (pre-weighted) + sg*sho --
__global__ __launch_bounds__(256) void combine_kernel(
    const float* __restrict__ x2, const float* __restrict__ sho,
    const float* __restrict__ sg, const float* __restrict__ cw,
    const int* __restrict__ posmat, const f16* __restrict__ eo,
    float* __restrict__ out) {
    long total = (long)T_ * D_ / 4;
    for (long i = (long)blockIdx.x * 256 + threadIdx.x; i < total;
         i += (long)gridDim.x * 256) {
        int t = (int)(i >> 9);
        int c4 = (int)(i & 511) * 4;
        float4 a = ((const float4*)x2)[i];
        float4 s = ((const float4*)sho)[i];
        float g = sg[t];
        float r0 = a.x + g * s.x, r1 = a.y + g * s.y;
        float r2 = a.z + g * s.z, r3 = a.w + g * s.w;
        #pragma unroll
        for (int e = 0; e < 8; e++) {
            float w = cw[(long)e * T_ + t];
            if (w > 0.f) {
                int slot = posmat[(long)e * T_ + t];
                f16x4 v = *(const f16x4*)(eo + ((long)e * T_ + slot) * D_ + c4);
                r0 += (float)v[0]; r1 += (float)v[1];
                r2 += (float)v[2]; r3 += (float)v[3];
            }
        }
        float4 o; o.x = r0; o.y = r1; o.z = r2; o.w = r3;
        ((float4*)out)[i] = o;
    }
}

extern "C" void kernel_launch(void* const* d_in, const int* in_sizes, int n_in,
                              void* d_out, int out_size, void* d_ws, size_t ws_size,
                              hipStream_t stream) {
    const float* x    = (const float*)d_in[0];
    const float* ln1  = (const float*)d_in[1];
    const float* ln2  = (const float*)d_in[2];
    const float* wq   = (const float*)d_in[3];
    const float* bq   = (const float*)d_in[4];
    const float* wk   = (const float*)d_in[5];
    const float* bk   = (const float*)d_in[6];
    const float* wv   = (const float*)d_in[7];
    const float* bv   = (const float*)d_in[8];
    const float* wo   = (const float*)d_in[9];
    const float* wrt  = (const float*)d_in[10];
    const float* wge  = (const float*)d_in[11];
    const float* wue  = (const float*)d_in[12];
    const float* wde  = (const float*)d_in[13];
    const float* wsg  = (const float*)d_in[14];
    const float* wsu  = (const float*)d_in[15];
    const float* wsd  = (const float*)d_in[16];
    const float* wshg = (const float*)d_in[17];

    float* ws = (float*)d_ws;
    f16*   wT     = (f16*)ws;                       // 11,534,336 floats
    float* x2     = ws + 11534336;                  // 2,097,152
    float* sho    = x2 + 2097152;                   // 2,097,152
    float* bqkv   = sho + 2097152;                  // 6,144
    float* cw     = bqkv + 6144;                    // 8,192
    float* sg     = cw + 8192;                      // 1,024
    int*   cnt    = (int*)(sg + 1024);              // 8
    int*   tokidx = cnt + 8;                        // 8,192
    float* tw     = (float*)(tokidx + 8192);        // 8,192
    int*   posmat = (int*)(tw + 8192);              // 8,192
    f16*   h1     = (f16*)(posmat + 8192);          // 1,048,576 floats
    f16*   h2     = (f16*)((float*)h1 + 1048576);   // 1,048,576 floats
    float* pool   = (float*)h2 + 1048576;           // 14,155,776 floats

    // pool phase aliases
    f16*   qkv     = (f16*)pool;                    // 3,145,728 floats
    float* woparts = pool + 3145728;                // 4,194,304 floats (2 planes)
    f16*   sgb     = (f16*)pool;                    // 2,883,584 floats
    float* parts4  = pool + 2883584;                // 8,388,608 floats (4 planes)
    f16*   Gg      = (f16*)pool;                    // 5,767,168 floats
    f16*   eo      = (f16*)(pool + 5767168);        // 8,388,608 floats
    f16*   ao      = h1;                            // alias (h1 dead after QKV GEMM)

    dim3 blk(256);

    // ---- attention block ----
    rmsnorm16_kernel<<<T_, blk, 0, stream>>>(x, ln1, h1);
    biascat_kernel<<<24, blk, 0, stream>>>(bq, bk, bv, bqkv);
    tconv_qkvo_kernel<<<dim3(32, 32, 4), blk, 0, stream>>>(wq, wk, wv, wo, wT);
    gemm16_kernel<1, 0><<<dim3(48, 8, 1), blk, 0, stream>>>(
        h1, wT, qkv, bqkv, nullptr, nullptr, nullptr,
        T_, QKVN, D_, 2048, 2048, 0, 0, 0);
    rope16_kernel<<<S_, blk, 0, stream>>>(qkv);
    attn16_kernel<<<dim3(16, 16), blk, 0, stream>>>(qkv, ao);
    // wo GEMM split-K=2 -> fp32 partials (wo weights at wT + 6144*2048)
    gemm16_kernel<4, 0><<<dim3(16, 8, 2), blk, 0, stream>>>(
        ao, wT + 6144L * 2048, woparts, nullptr, nullptr, nullptr, nullptr,
        T_, D_, 1024, 2048, 2048, 1024, 1024, 2097152);
    // fused: x2 = x + p0 + p1; h2 = rms(x2); router top-4 + shared gate
    postattn_kernel<<<T_, blk, 0, stream>>>(x, woparts, ln2, wrt, wshg, x2, h2, cw, sg);
    bucket_kernel<<<1, 512, 0, stream>>>(cw, cnt, tokidx, tw, posmat);

    // shared expert: fused gate+up (one dual-source tconv), then split-K=4 down
    tconv_gu_kernel<<<dim3(88, 32, 2), blk, 0, stream>>>(wsg, wsu, wT, 2048, 5632, 0, 0, 1);
    gemm16_kernel<5, 0><<<dim3(88, 8, 1), blk, 0, stream>>>(
        h2, wT, sgb, nullptr, nullptr, nullptr, nullptr,
        T_, 2 * FS_, D_, 2048, 2048, 0, 0, 0);
    tconv_kernel<<<dim3(32, 88, 1), blk, 0, stream>>>(wsd, wT, 5632, 2048, 0, 0);
    gemm16_kernel<4, 0><<<dim3(16, 8, 4), blk, 0, stream>>>(
        sgb, wT, parts4, nullptr, nullptr, nullptr, nullptr,
        T_, D_, 1408, 5632, 5632, 1408, 1408, 2097152);
    reduce4_kernel<<<512, blk, 0, stream>>>(parts4, sho);

    // routed experts (top-4 sparse), batch 1 (e0-3): dual-source gate+up tconv
    tconv_gu_kernel<<<dim3(22, 32, 8), blk, 0, stream>>>(
        wge, wue, wT, 2048, 1408, 2048L * 1408, 2816L * 2048, 4);
    gemm16_kernel<5, 1><<<dim3(22, 8, 4), blk, 0, stream>>>(
        h2, wT, Gg, nullptr, tokidx, cnt, nullptr,
        T_, 2 * FI_, D_, 2048, 2048, 0, 2816L * 2048, 1024L * 1408);
    // batch 2 (e4-7)
    tconv_gu_kernel<<<dim3(22, 32, 8), blk, 0, stream>>>(
        wge + 4L * 2048 * 1408, wue + 4L * 2048 * 1408, wT, 2048, 1408,
        2048L * 1408, 2816L * 2048, 4);
    gemm16_kernel<5, 1><<<dim3(22, 8, 4), blk, 0, stream>>>(
        h2, wT, Gg + 4L * 1024 * 1408, nullptr, tokidx + 4 * T_, cnt + 4, nullptr,
        T_, 2 * FI_, D_, 2048, 2048, 0, 2816L * 2048, 1024L * 1408);

    // down: all 8 experts in one tconv + one GEMM
    tconv_kernel<<<dim3(32, 22, 8), blk, 0, stream>>>(wde, wT, 1408, 2048,
                                                      1408L * 2048, 2048L * 1408);
    gemm16_kernel<6, 2><<<dim3(16, 8, 8), blk, 0, stream>>>(
        Gg, wT, eo, nullptr, nullptr, cnt, tw,
        T_, D_, 1408, 1408, 1408, 1024L * 1408, 2048L * 1408, 1024L * 2048);

    combine_kernel<<<1024, blk, 0, stream>>>(x2, sho, sg, cw, posmat, eo, (float*)d_out);
}